// Round 1
// baseline (9692.056 us; speedup 1.0000x reference)
//
#include <hip/hip_runtime.h>
#include <hip/hip_bf16.h>
#include <stdint.h>

#define D 128
#define H 8
#define DK 16

// ---------- bf16 helpers ----------
__device__ __forceinline__ unsigned short f2bf(float f) {
    unsigned int u = __float_as_uint(f);
    u = u + 0x7fffu + ((u >> 16) & 1u);      // round-to-nearest-even
    return (unsigned short)(u >> 16);
}
__device__ __forceinline__ float bfl(unsigned int u) { return __uint_as_float(u << 16); }
__device__ __forceinline__ float bfh(unsigned int u) { return __uint_as_float(u & 0xffff0000u); }
__device__ __forceinline__ unsigned int pack2(unsigned short a, unsigned short b) {
    return (unsigned int)a | ((unsigned int)b << 16);
}
__device__ __forceinline__ void unpack8(uint4 u, float* o) {
    o[0]=bfl(u.x); o[1]=bfh(u.x); o[2]=bfl(u.y); o[3]=bfh(u.y);
    o[4]=bfl(u.z); o[5]=bfh(u.z); o[6]=bfl(u.w); o[7]=bfh(u.w);
}

// ---------- fused K/Q/V projection: out_m = bf16(x @ W_m + b_m), m in {k,q,v} ----------
// block: 256 thr = 32 colgroups(4 cols) x 8 rowgroups(8 rows); 64 rows/block.
__global__ __launch_bounds__(256) void proj3_kernel(
    const float* __restrict__ X,
    const float* __restrict__ W0, const float* __restrict__ b0, unsigned short* __restrict__ O0,
    const float* __restrict__ W1, const float* __restrict__ b1, unsigned short* __restrict__ O1,
    const float* __restrict__ W2, const float* __restrict__ b2, unsigned short* __restrict__ O2,
    int N)
{
    __shared__ float xT[64 * 68];   // [kk][row], stride 68 (16B aligned, bank-spread)
    __shared__ float Wl[64 * 128];  // [kk][c]
    const int tid = threadIdx.x;
    const int cg = tid & 31;
    const int rg = tid >> 5;
    const int row0 = blockIdx.x * 64;

    const float* Ws[3] = {W0, W1, W2};
    const float* bs[3] = {b0, b1, b2};
    unsigned short* Os[3] = {O0, O1, O2};

    #pragma unroll
    for (int m = 0; m < 3; ++m) {
        float acc[8][4];
        #pragma unroll
        for (int j = 0; j < 8; ++j)
            #pragma unroll
            for (int c = 0; c < 4; ++c) acc[j][c] = 0.f;

        for (int kk0 = 0; kk0 < 128; kk0 += 64) {
            __syncthreads();
            // stage W chunk [64][128]
            #pragma unroll
            for (int i = 0; i < 32; ++i) {
                int idx = i * 256 + tid;
                int kk = idx >> 7, c = idx & 127;
                Wl[kk * 128 + c] = Ws[m][(size_t)(kk0 + kk) * 128 + c];
            }
            // stage x chunk transposed [64 kk][64 rows]
            #pragma unroll
            for (int i = 0; i < 16; ++i) {
                int idx = i * 256 + tid;
                int kk = idx & 63, r = idx >> 6;
                int row = row0 + r; if (row >= N) row = N - 1;
                xT[kk * 68 + r] = X[(size_t)row * 128 + kk0 + kk];
            }
            __syncthreads();
            #pragma unroll 4
            for (int kk = 0; kk < 64; ++kk) {
                float4 wv = *(const float4*)&Wl[kk * 128 + cg * 4];
                float4 xa = *(const float4*)&xT[kk * 68 + rg * 8];
                float4 xb = *(const float4*)&xT[kk * 68 + rg * 8 + 4];
                float xr[8] = {xa.x, xa.y, xa.z, xa.w, xb.x, xb.y, xb.z, xb.w};
                float wc[4] = {wv.x, wv.y, wv.z, wv.w};
                #pragma unroll
                for (int j = 0; j < 8; ++j)
                    #pragma unroll
                    for (int c = 0; c < 4; ++c)
                        acc[j][c] = fmaf(xr[j], wc[c], acc[j][c]);
            }
        }
        float4 bv = *(const float4*)&bs[m][cg * 4];
        float bb[4] = {bv.x, bv.y, bv.z, bv.w};
        #pragma unroll
        for (int j = 0; j < 8; ++j) {
            int row = row0 + rg * 8 + j;
            if (row < N) {
                unsigned int lo = pack2(f2bf(acc[j][0] + bb[0]), f2bf(acc[j][1] + bb[1]));
                unsigned int hi = pack2(f2bf(acc[j][2] + bb[2]), f2bf(acc[j][3] + bb[3]));
                *(uint2*)&Os[m][(size_t)row * 128 + cg * 4] = make_uint2(lo, hi);
            }
        }
        __syncthreads();
    }
}

// ---------- per-node 16x16 head transform ----------
// MODE 0 (qhat): out[h][d] = sum_f R[h][d][f] * in[h][f]
// MODE 1 (vhat): out[h][f] = sum_d R[h][d][f] * in[h][d]
template<int MODE>
__global__ __launch_bounds__(256) void node_transform_kernel(
    const unsigned short* __restrict__ IN, const float* __restrict__ R,
    unsigned short* __restrict__ OUT, int N)
{
    __shared__ float Rl[H * 257];
    const int tid = threadIdx.x;
    #pragma unroll
    for (int i = 0; i < 8; ++i) {
        int idx = i * 256 + tid;
        Rl[(idx >> 8) * 257 + (idx & 255)] = R[idx];
    }
    __syncthreads();
    int gid = blockIdx.x * 256 + tid;
    int n = gid >> 3, h = gid & 7;
    if (n >= N) return;
    const uint4* ip = (const uint4*)(IN + (size_t)n * D + h * DK);
    uint4 i0 = ip[0], i1 = ip[1];
    float inv[16];
    unpack8(i0, inv); unpack8(i1, inv + 8);
    const float* Rh = &Rl[h * 257];
    unsigned short ob[16];
    #pragma unroll
    for (int d = 0; d < 16; ++d) {
        float s = 0.f;
        #pragma unroll
        for (int f = 0; f < 16; ++f) {
            float r = (MODE == 0) ? Rh[d * 16 + f] : Rh[f * 16 + d];
            s = fmaf(r, inv[f], s);
        }
        ob[d] = f2bf(s);
    }
    uint4 o0, o1;
    o0.x = pack2(ob[0], ob[1]);  o0.y = pack2(ob[2], ob[3]);
    o0.z = pack2(ob[4], ob[5]);  o0.w = pack2(ob[6], ob[7]);
    o1.x = pack2(ob[8], ob[9]);  o1.y = pack2(ob[10], ob[11]);
    o1.z = pack2(ob[12], ob[13]); o1.w = pack2(ob[14], ob[15]);
    uint4* op = (uint4*)(OUT + (size_t)n * D + h * DK);
    op[0] = o0; op[1] = o1;
}

// ---------- edge pass 1: ea = exp(pri/4 * dot16(k_src, qhat_dst)); denom[dst,h] += ea ----------
__global__ __launch_bounds__(256) void edge_logits_kernel(
    const int* __restrict__ src, const int* __restrict__ dst,
    const unsigned short* __restrict__ K, const unsigned short* __restrict__ QH,
    const float* __restrict__ pri, float* __restrict__ EA, float* __restrict__ DEN, int E)
{
    int gid = blockIdx.x * 256 + threadIdx.x;
    int e = gid >> 3, h = gid & 7;
    if (e >= E) return;
    int s = src[e], d = dst[e];
    const uint4* kp = (const uint4*)(K + (size_t)s * D + h * DK);
    const uint4* qp = (const uint4*)(QH + (size_t)d * D + h * DK);
    uint4 k0 = kp[0], k1 = kp[1], q0 = qp[0], q1 = qp[1];
    float kv[16], qv[16];
    unpack8(k0, kv); unpack8(k1, kv + 8);
    unpack8(q0, qv); unpack8(q1, qv + 8);
    float a = 0.f;
    #pragma unroll
    for (int i = 0; i < 16; ++i) a = fmaf(kv[i], qv[i], a);
    a *= pri[h] * 0.25f;
    float ea = __expf(a);
    EA[gid] = ea;
    atomicAdd(&DEN[(size_t)d * H + h], ea);
}

// ---------- edge pass 2: t[dst] += (ea/denom) * vhat_src ----------
__global__ __launch_bounds__(256) void edge_agg_kernel(
    const int* __restrict__ src, const int* __restrict__ dst,
    const float* __restrict__ EA, const float* __restrict__ DEN,
    const unsigned short* __restrict__ VH, float* __restrict__ T, int E)
{
    int gid = blockIdx.x * 256 + threadIdx.x;
    int e = gid >> 3, h = gid & 7;
    if (e >= E) return;
    int s = src[e], d = dst[e];
    float w = EA[gid] / DEN[(size_t)d * H + h];
    const uint4* vp = (const uint4*)(VH + (size_t)s * D + h * DK);
    uint4 v0 = vp[0], v1 = vp[1];
    float vv[16];
    unpack8(v0, vv); unpack8(v1, vv + 8);
    float* tp = T + (size_t)d * D + h * DK;
    #pragma unroll
    for (int i = 0; i < 16; ++i) atomicAdd(tp + i, w * vv[i]);
}

// ---------- final: out = (relu-combined(t) @ Wa + ba)*alpha + x*(1-alpha) ----------
template<int NSRC>
__global__ __launch_bounds__(256) void out_gemm_kernel(
    const float* __restrict__ T1, const float* __restrict__ T2,
    const float* __restrict__ W, const float* __restrict__ b,
    const float* __restrict__ skip, const float* __restrict__ X,
    float* __restrict__ O, int N)
{
    __shared__ float xT[64 * 68];
    __shared__ float Wl[64 * 128];
    const int tid = threadIdx.x;
    const int cg = tid & 31;
    const int rg = tid >> 5;
    const int row0 = blockIdx.x * 64;

    float acc[8][4];
    #pragma unroll
    for (int j = 0; j < 8; ++j)
        #pragma unroll
        for (int c = 0; c < 4; ++c) acc[j][c] = 0.f;

    for (int kk0 = 0; kk0 < 128; kk0 += 64) {
        __syncthreads();
        #pragma unroll
        for (int i = 0; i < 32; ++i) {
            int idx = i * 256 + tid;
            int kk = idx >> 7, c = idx & 127;
            Wl[kk * 128 + c] = W[(size_t)(kk0 + kk) * 128 + c];
        }
        #pragma unroll
        for (int i = 0; i < 16; ++i) {
            int idx = i * 256 + tid;
            int kk = idx & 63, r = idx >> 6;
            int row = row0 + r; if (row >= N) row = N - 1;
            float v = T1[(size_t)row * 128 + kk0 + kk];
            v = fmaxf(v, 0.f);
            if (NSRC == 2) {
                float v2 = fmaxf(T2[(size_t)row * 128 + kk0 + kk], 0.f);
                v = 0.5f * (v + v2);
            }
            xT[kk * 68 + r] = v;
        }
        __syncthreads();
        #pragma unroll 4
        for (int kk = 0; kk < 64; ++kk) {
            float4 wv = *(const float4*)&Wl[kk * 128 + cg * 4];
            float4 xa = *(const float4*)&xT[kk * 68 + rg * 8];
            float4 xb = *(const float4*)&xT[kk * 68 + rg * 8 + 4];
            float xr[8] = {xa.x, xa.y, xa.z, xa.w, xb.x, xb.y, xb.z, xb.w};
            float wc[4] = {wv.x, wv.y, wv.z, wv.w};
            #pragma unroll
            for (int j = 0; j < 8; ++j)
                #pragma unroll
                for (int c = 0; c < 4; ++c)
                    acc[j][c] = fmaf(xr[j], wc[c], acc[j][c]);
        }
    }
    float alpha = 1.f / (1.f + __expf(-skip[0]));
    float om = 1.f - alpha;
    float4 bv = *(const float4*)&b[cg * 4];
    float bb[4] = {bv.x, bv.y, bv.z, bv.w};
    #pragma unroll
    for (int j = 0; j < 8; ++j) {
        int row = row0 + rg * 8 + j;
        if (row < N) {
            float4 xv = *(const float4*)&X[(size_t)row * 128 + cg * 4];
            float4 ov;
            ov.x = (acc[j][0] + bb[0]) * alpha + xv.x * om;
            ov.y = (acc[j][1] + bb[1]) * alpha + xv.y * om;
            ov.z = (acc[j][2] + bb[2]) * alpha + xv.z * om;
            ov.w = (acc[j][3] + bb[3]) * alpha + xv.w * om;
            *(float4*)&O[(size_t)row * 128 + cg * 4] = ov;
        }
    }
}

extern "C" void kernel_launch(void* const* d_in, const int* in_sizes, int n_in,
                              void* d_out, int out_size, void* d_ws, size_t ws_size,
                              hipStream_t stream) {
    const float* x_a = (const float*)d_in[0];
    const float* x_b = (const float*)d_in[1];
    const int* src_ab = (const int*)d_in[2];
    const int* dst_ab = (const int*)d_in[3];
    const int* src_ba = (const int*)d_in[4];
    const int* dst_ba = (const int*)d_in[5];
    const int* src_bb = (const int*)d_in[6];
    const int* dst_bb = (const int*)d_in[7];
    const float* Wk_a = (const float*)d_in[8];  const float* bk_a = (const float*)d_in[9];
    const float* Wq_a = (const float*)d_in[10]; const float* bq_a = (const float*)d_in[11];
    const float* Wv_a = (const float*)d_in[12]; const float* bv_a = (const float*)d_in[13];
    const float* Wa_a = (const float*)d_in[14]; const float* ba_a = (const float*)d_in[15];
    const float* skip_a = (const float*)d_in[16];
    const float* Wk_b = (const float*)d_in[17]; const float* bk_b = (const float*)d_in[18];
    const float* Wq_b = (const float*)d_in[19]; const float* bq_b = (const float*)d_in[20];
    const float* Wv_b = (const float*)d_in[21]; const float* bv_b = (const float*)d_in[22];
    const float* Wa_b = (const float*)d_in[23]; const float* ba_b = (const float*)d_in[24];
    const float* skip_b = (const float*)d_in[25];
    const float* pri_ab = (const float*)d_in[26];
    const float* att_ab = (const float*)d_in[27];
    const float* msg_ab = (const float*)d_in[28];
    const float* pri_ba = (const float*)d_in[29];
    const float* att_ba = (const float*)d_in[30];
    const float* msg_ba = (const float*)d_in[31];
    const float* pri_bb = (const float*)d_in[32];
    const float* att_bb = (const float*)d_in[33];
    const float* msg_bb = (const float*)d_in[34];

    const int n_a = in_sizes[0] / D;
    const int n_b = in_sizes[1] / D;
    const int E = in_sizes[2];
    const int nmax = (n_a > n_b) ? n_a : n_b;

    // workspace layout (bump allocator, 256B aligned)
    size_t off = 0;
    char* base = (char*)d_ws;
    auto alloc = [&](size_t bytes) -> void* {
        void* r = base + off;
        off += (bytes + 255) & ~(size_t)255;
        return r;
    };
    unsigned short* k_a = (unsigned short*)alloc((size_t)n_a * D * 2);
    unsigned short* q_a = (unsigned short*)alloc((size_t)n_a * D * 2);
    unsigned short* v_a = (unsigned short*)alloc((size_t)n_a * D * 2);
    unsigned short* k_b = (unsigned short*)alloc((size_t)n_b * D * 2);
    unsigned short* q_b = (unsigned short*)alloc((size_t)n_b * D * 2);
    unsigned short* v_b = (unsigned short*)alloc((size_t)n_b * D * 2);
    unsigned short* qhat = (unsigned short*)alloc((size_t)nmax * D * 2);
    unsigned short* vhat = (unsigned short*)alloc((size_t)nmax * D * 2);
    float* ea = (float*)alloc((size_t)E * H * 4);
    float* den_ab = (float*)alloc((size_t)n_b * H * 4);
    float* den_ba = (float*)alloc((size_t)n_a * H * 4);
    float* den_bb = (float*)alloc((size_t)n_b * H * 4);
    float* t_a  = (float*)alloc((size_t)n_a * D * 4);
    float* t_b1 = (float*)alloc((size_t)n_b * D * 4);
    float* t_b2 = (float*)alloc((size_t)n_b * D * 4);

    // zero accumulators (must be re-done every launch: harness does not re-poison)
    hipMemsetAsync(den_ab, 0, (size_t)n_b * H * 4, stream);
    hipMemsetAsync(den_ba, 0, (size_t)n_a * H * 4, stream);
    hipMemsetAsync(den_bb, 0, (size_t)n_b * H * 4, stream);
    hipMemsetAsync(t_a,  0, (size_t)n_a * D * 4, stream);
    hipMemsetAsync(t_b1, 0, (size_t)n_b * D * 4, stream);
    hipMemsetAsync(t_b2, 0, (size_t)n_b * D * 4, stream);

    const int gb_a = (n_a + 63) / 64;
    const int gb_b = (n_b + 63) / 64;
    const int gt_a = (n_a * H + 255) / 256;
    const int gt_b = (n_b * H + 255) / 256;
    const int ge   = (E * H + 255) / 256;

    // K/Q/V projections
    proj3_kernel<<<gb_a, 256, 0, stream>>>(x_a, Wk_a, bk_a, k_a, Wq_a, bq_a, q_a, Wv_a, bv_a, v_a, n_a);
    proj3_kernel<<<gb_b, 256, 0, stream>>>(x_b, Wk_b, bk_b, k_b, Wq_b, bq_b, q_b, Wv_b, bv_b, v_b, n_b);

    // etype ab: k_a -> q_b, v_a, accumulate into t_b1
    node_transform_kernel<0><<<gt_b, 256, 0, stream>>>(q_b, att_ab, qhat, n_b);
    node_transform_kernel<1><<<gt_a, 256, 0, stream>>>(v_a, msg_ab, vhat, n_a);
    edge_logits_kernel<<<ge, 256, 0, stream>>>(src_ab, dst_ab, k_a, qhat, pri_ab, ea, den_ab, E);
    edge_agg_kernel<<<ge, 256, 0, stream>>>(src_ab, dst_ab, ea, den_ab, vhat, t_b1, E);

    // etype bb: k_b -> q_b, v_b, accumulate into t_b2
    node_transform_kernel<0><<<gt_b, 256, 0, stream>>>(q_b, att_bb, qhat, n_b);
    node_transform_kernel<1><<<gt_b, 256, 0, stream>>>(v_b, msg_bb, vhat, n_b);
    edge_logits_kernel<<<ge, 256, 0, stream>>>(src_bb, dst_bb, k_b, qhat, pri_bb, ea, den_bb, E);
    edge_agg_kernel<<<ge, 256, 0, stream>>>(src_bb, dst_bb, ea, den_bb, vhat, t_b2, E);

    // etype ba: k_b -> q_a, v_b, accumulate into t_a
    node_transform_kernel<0><<<gt_a, 256, 0, stream>>>(q_a, att_ba, qhat, n_a);
    node_transform_kernel<1><<<gt_b, 256, 0, stream>>>(v_b, msg_ba, vhat, n_b);
    edge_logits_kernel<<<ge, 256, 0, stream>>>(src_ba, dst_ba, k_b, qhat, pri_ba, ea, den_ba, E);
    edge_agg_kernel<<<ge, 256, 0, stream>>>(src_ba, dst_ba, ea, den_ba, vhat, t_a, E);

    // final skip-connection GEMMs
    float* out_a = (float*)d_out;
    float* out_b = (float*)d_out + (size_t)n_a * D;
    out_gemm_kernel<1><<<gb_a, 256, 0, stream>>>(t_a, nullptr, Wa_a, ba_a, skip_a, x_a, out_a, n_a);
    out_gemm_kernel<2><<<gb_b, 256, 0, stream>>>(t_b1, t_b2, Wa_b, ba_b, skip_b, x_b, out_b, n_b);
}

// Round 2
// 1203.796 us; speedup vs baseline: 8.0512x; 8.0512x over previous
//
#include <hip/hip_runtime.h>
#include <hip/hip_bf16.h>
#include <stdint.h>

#define D 128
#define H 8
#define DK 16

#define SCAN_BLK 256
#define SCAN_ITEMS 8
#define SCAN_TILE (SCAN_BLK * SCAN_ITEMS)

// ---------- bf16 helpers ----------
__device__ __forceinline__ unsigned short f2bf(float f) {
    unsigned int u = __float_as_uint(f);
    u = u + 0x7fffu + ((u >> 16) & 1u);      // round-to-nearest-even
    return (unsigned short)(u >> 16);
}
__device__ __forceinline__ float bfl(unsigned int u) { return __uint_as_float(u << 16); }
__device__ __forceinline__ float bfh(unsigned int u) { return __uint_as_float(u & 0xffff0000u); }
__device__ __forceinline__ unsigned int pack2(unsigned short a, unsigned short b) {
    return (unsigned int)a | ((unsigned int)b << 16);
}
__device__ __forceinline__ void unpack8(uint4 u, float* o) {
    o[0]=bfl(u.x); o[1]=bfh(u.x); o[2]=bfl(u.y); o[3]=bfh(u.y);
    o[4]=bfl(u.z); o[5]=bfh(u.z); o[6]=bfl(u.w); o[7]=bfh(u.w);
}

// ---------- fused K/Q/V projection: out_m = bf16(x @ W_m + b_m), m in {k,q,v} ----------
__global__ __launch_bounds__(256) void proj3_kernel(
    const float* __restrict__ X,
    const float* __restrict__ W0, const float* __restrict__ b0, unsigned short* __restrict__ O0,
    const float* __restrict__ W1, const float* __restrict__ b1, unsigned short* __restrict__ O1,
    const float* __restrict__ W2, const float* __restrict__ b2, unsigned short* __restrict__ O2,
    int N)
{
    __shared__ float xT[64 * 68];
    __shared__ float Wl[64 * 128];
    const int tid = threadIdx.x;
    const int cg = tid & 31;
    const int rg = tid >> 5;
    const int row0 = blockIdx.x * 64;

    const float* Ws[3] = {W0, W1, W2};
    const float* bs[3] = {b0, b1, b2};
    unsigned short* Os[3] = {O0, O1, O2};

    #pragma unroll
    for (int m = 0; m < 3; ++m) {
        float acc[8][4];
        #pragma unroll
        for (int j = 0; j < 8; ++j)
            #pragma unroll
            for (int c = 0; c < 4; ++c) acc[j][c] = 0.f;

        for (int kk0 = 0; kk0 < 128; kk0 += 64) {
            __syncthreads();
            #pragma unroll
            for (int i = 0; i < 32; ++i) {
                int idx = i * 256 + tid;
                int kk = idx >> 7, c = idx & 127;
                Wl[kk * 128 + c] = Ws[m][(size_t)(kk0 + kk) * 128 + c];
            }
            #pragma unroll
            for (int i = 0; i < 16; ++i) {
                int idx = i * 256 + tid;
                int kk = idx & 63, r = idx >> 6;
                int row = row0 + r; if (row >= N) row = N - 1;
                xT[kk * 68 + r] = X[(size_t)row * 128 + kk0 + kk];
            }
            __syncthreads();
            #pragma unroll 4
            for (int kk = 0; kk < 64; ++kk) {
                float4 wv = *(const float4*)&Wl[kk * 128 + cg * 4];
                float4 xa = *(const float4*)&xT[kk * 68 + rg * 8];
                float4 xb = *(const float4*)&xT[kk * 68 + rg * 8 + 4];
                float xr[8] = {xa.x, xa.y, xa.z, xa.w, xb.x, xb.y, xb.z, xb.w};
                float wc[4] = {wv.x, wv.y, wv.z, wv.w};
                #pragma unroll
                for (int j = 0; j < 8; ++j)
                    #pragma unroll
                    for (int c = 0; c < 4; ++c)
                        acc[j][c] = fmaf(xr[j], wc[c], acc[j][c]);
            }
        }
        float4 bv = *(const float4*)&bs[m][cg * 4];
        float bb[4] = {bv.x, bv.y, bv.z, bv.w};
        #pragma unroll
        for (int j = 0; j < 8; ++j) {
            int row = row0 + rg * 8 + j;
            if (row < N) {
                unsigned int lo = pack2(f2bf(acc[j][0] + bb[0]), f2bf(acc[j][1] + bb[1]));
                unsigned int hi = pack2(f2bf(acc[j][2] + bb[2]), f2bf(acc[j][3] + bb[3]));
                *(uint2*)&Os[m][(size_t)row * 128 + cg * 4] = make_uint2(lo, hi);
            }
        }
        __syncthreads();
    }
}

// ---------- per-node 16x16 head transform ----------
template<int MODE>
__global__ __launch_bounds__(256) void node_transform_kernel(
    const unsigned short* __restrict__ IN, const float* __restrict__ R,
    unsigned short* __restrict__ OUT, int N)
{
    __shared__ float Rl[H * 257];
    const int tid = threadIdx.x;
    #pragma unroll
    for (int i = 0; i < 8; ++i) {
        int idx = i * 256 + tid;
        Rl[(idx >> 8) * 257 + (idx & 255)] = R[idx];
    }
    __syncthreads();
    int gid = blockIdx.x * 256 + tid;
    int n = gid >> 3, h = gid & 7;
    if (n >= N) return;
    const uint4* ip = (const uint4*)(IN + (size_t)n * D + h * DK);
    uint4 i0 = ip[0], i1 = ip[1];
    float inv[16];
    unpack8(i0, inv); unpack8(i1, inv + 8);
    const float* Rh = &Rl[h * 257];
    unsigned short ob[16];
    #pragma unroll
    for (int d = 0; d < 16; ++d) {
        float s = 0.f;
        #pragma unroll
        for (int f = 0; f < 16; ++f) {
            float r = (MODE == 0) ? Rh[d * 16 + f] : Rh[f * 16 + d];
            s = fmaf(r, inv[f], s);
        }
        ob[d] = f2bf(s);
    }
    uint4 o0, o1;
    o0.x = pack2(ob[0], ob[1]);  o0.y = pack2(ob[2], ob[3]);
    o0.z = pack2(ob[4], ob[5]);  o0.w = pack2(ob[6], ob[7]);
    o1.x = pack2(ob[8], ob[9]);  o1.y = pack2(ob[10], ob[11]);
    o1.z = pack2(ob[12], ob[13]); o1.w = pack2(ob[14], ob[15]);
    uint4* op = (uint4*)(OUT + (size_t)n * D + h * DK);
    op[0] = o0; op[1] = o1;
}

// ---------- CSR build: histogram -> scan -> scatter ----------
__global__ __launch_bounds__(256) void hist_kernel(const int* __restrict__ dst, int* __restrict__ cnt, int E) {
    int e = blockIdx.x * 256 + threadIdx.x;
    if (e < E) atomicAdd(&cnt[dst[e]], 1);
}

__global__ __launch_bounds__(SCAN_BLK) void scan1_kernel(const int* __restrict__ cnt, int* __restrict__ bsum, int n) {
    __shared__ int sh[SCAN_BLK];
    int base = blockIdx.x * SCAN_TILE + threadIdx.x * SCAN_ITEMS;
    int s = 0;
    #pragma unroll
    for (int i = 0; i < SCAN_ITEMS; ++i) {
        int idx = base + i;
        if (idx < n) s += cnt[idx];
    }
    sh[threadIdx.x] = s; __syncthreads();
    for (int o = SCAN_BLK / 2; o > 0; o >>= 1) {
        if (threadIdx.x < o) sh[threadIdx.x] += sh[threadIdx.x + o];
        __syncthreads();
    }
    if (threadIdx.x == 0) bsum[blockIdx.x] = sh[0];
}

__global__ void scan2_kernel(int* __restrict__ bsum, int nb) {
    if (threadIdx.x == 0 && blockIdx.x == 0) {
        int acc = 0;
        for (int i = 0; i < nb; ++i) { int v = bsum[i]; bsum[i] = acc; acc += v; }
    }
}

__global__ __launch_bounds__(SCAN_BLK) void scan3_kernel(
    const int* __restrict__ cnt, const int* __restrict__ bsum,
    int* __restrict__ offs, int* __restrict__ cursor, int n)
{
    __shared__ int sh[SCAN_BLK];
    int base = blockIdx.x * SCAN_TILE + threadIdx.x * SCAN_ITEMS;
    int v[SCAN_ITEMS];
    int s = 0;
    #pragma unroll
    for (int i = 0; i < SCAN_ITEMS; ++i) {
        int idx = base + i;
        v[i] = (idx < n) ? cnt[idx] : 0;
        s += v[i];
    }
    sh[threadIdx.x] = s; __syncthreads();
    // Hillis-Steele inclusive scan
    for (int o = 1; o < SCAN_BLK; o <<= 1) {
        int t = (threadIdx.x >= o) ? sh[threadIdx.x - o] : 0;
        __syncthreads();
        sh[threadIdx.x] += t;
        __syncthreads();
    }
    int off = bsum[blockIdx.x] + sh[threadIdx.x] - s;   // exclusive offset for this thread
    #pragma unroll
    for (int i = 0; i < SCAN_ITEMS; ++i) {
        int idx = base + i;
        if (idx < n) {
            offs[idx] = off;
            cursor[idx] = off;
            off += v[i];
            if (idx == n - 1) offs[n] = off;
        }
    }
}

__global__ __launch_bounds__(256) void scatter_kernel(
    const int* __restrict__ src, const int* __restrict__ dst,
    int* __restrict__ cursor, int* __restrict__ csr_src, int E)
{
    int e = blockIdx.x * 256 + threadIdx.x;
    if (e < E) {
        int p = atomicAdd(&cursor[dst[e]], 1);
        csr_src[p] = src[e];
    }
}

// ---------- fused per-dst softmax + aggregate over CSR segment ----------
// thread = (n, h); single pass: t[n,h,:] = (sum_e ea*vhat_src) / (sum_e ea)
__global__ __launch_bounds__(256) void csr_agg_kernel(
    const int* __restrict__ offs, const int* __restrict__ csr_src,
    const unsigned short* __restrict__ K, const unsigned short* __restrict__ QH,
    const unsigned short* __restrict__ VH, const float* __restrict__ pri,
    float* __restrict__ T, int n_dst)
{
    int gid = blockIdx.x * 256 + threadIdx.x;
    int n = gid >> 3, h = gid & 7;
    if (n >= n_dst) return;
    int e0 = offs[n], e1 = offs[n + 1];

    const uint4* qp = (const uint4*)(QH + (size_t)n * D + h * DK);
    uint4 q0 = qp[0], q1 = qp[1];
    float qv[16];
    unpack8(q0, qv); unpack8(q1, qv + 8);
    float ps = pri[h] * 0.25f;

    float acc[16];
    #pragma unroll
    for (int i = 0; i < 16; ++i) acc[i] = 0.f;
    float den = 0.f;

    for (int e = e0; e < e1; ++e) {
        int s = csr_src[e];
        const uint4* kp = (const uint4*)(K + (size_t)s * D + h * DK);
        uint4 k0 = kp[0], k1 = kp[1];
        float kv[16];
        unpack8(k0, kv); unpack8(k1, kv + 8);
        float a = 0.f;
        #pragma unroll
        for (int i = 0; i < 16; ++i) a = fmaf(kv[i], qv[i], a);
        float ea = __expf(a * ps);
        den += ea;
        const uint4* vp = (const uint4*)(VH + (size_t)s * D + h * DK);
        uint4 v0 = vp[0], v1 = vp[1];
        float vv[16];
        unpack8(v0, vv); unpack8(v1, vv + 8);
        #pragma unroll
        for (int i = 0; i < 16; ++i) acc[i] = fmaf(ea, vv[i], acc[i]);
    }
    float inv = 1.f / fmaxf(den, 1e-9f);
    float4 o0, o1, o2, o3;
    o0 = make_float4(acc[0]*inv, acc[1]*inv, acc[2]*inv, acc[3]*inv);
    o1 = make_float4(acc[4]*inv, acc[5]*inv, acc[6]*inv, acc[7]*inv);
    o2 = make_float4(acc[8]*inv, acc[9]*inv, acc[10]*inv, acc[11]*inv);
    o3 = make_float4(acc[12]*inv, acc[13]*inv, acc[14]*inv, acc[15]*inv);
    float* tp = T + (size_t)n * D + h * DK;
    *(float4*)(tp + 0)  = o0;
    *(float4*)(tp + 4)  = o1;
    *(float4*)(tp + 8)  = o2;
    *(float4*)(tp + 12) = o3;
}

// ---------- final: out = (relu-combined(t) @ Wa + ba)*alpha + x*(1-alpha) ----------
template<int NSRC>
__global__ __launch_bounds__(256) void out_gemm_kernel(
    const float* __restrict__ T1, const float* __restrict__ T2,
    const float* __restrict__ W, const float* __restrict__ b,
    const float* __restrict__ skip, const float* __restrict__ X,
    float* __restrict__ O, int N)
{
    __shared__ float xT[64 * 68];
    __shared__ float Wl[64 * 128];
    const int tid = threadIdx.x;
    const int cg = tid & 31;
    const int rg = tid >> 5;
    const int row0 = blockIdx.x * 64;

    float acc[8][4];
    #pragma unroll
    for (int j = 0; j < 8; ++j)
        #pragma unroll
        for (int c = 0; c < 4; ++c) acc[j][c] = 0.f;

    for (int kk0 = 0; kk0 < 128; kk0 += 64) {
        __syncthreads();
        #pragma unroll
        for (int i = 0; i < 32; ++i) {
            int idx = i * 256 + tid;
            int kk = idx >> 7, c = idx & 127;
            Wl[kk * 128 + c] = W[(size_t)(kk0 + kk) * 128 + c];
        }
        #pragma unroll
        for (int i = 0; i < 16; ++i) {
            int idx = i * 256 + tid;
            int kk = idx & 63, r = idx >> 6;
            int row = row0 + r; if (row >= N) row = N - 1;
            float v = T1[(size_t)row * 128 + kk0 + kk];
            v = fmaxf(v, 0.f);
            if (NSRC == 2) {
                float v2 = fmaxf(T2[(size_t)row * 128 + kk0 + kk], 0.f);
                v = 0.5f * (v + v2);
            }
            xT[kk * 68 + r] = v;
        }
        __syncthreads();
        #pragma unroll 4
        for (int kk = 0; kk < 64; ++kk) {
            float4 wv = *(const float4*)&Wl[kk * 128 + cg * 4];
            float4 xa = *(const float4*)&xT[kk * 68 + rg * 8];
            float4 xb = *(const float4*)&xT[kk * 68 + rg * 8 + 4];
            float xr[8] = {xa.x, xa.y, xa.z, xa.w, xb.x, xb.y, xb.z, xb.w};
            float wc[4] = {wv.x, wv.y, wv.z, wv.w};
            #pragma unroll
            for (int j = 0; j < 8; ++j)
                #pragma unroll
                for (int c = 0; c < 4; ++c)
                    acc[j][c] = fmaf(xr[j], wc[c], acc[j][c]);
        }
    }
    float alpha = 1.f / (1.f + __expf(-skip[0]));
    float om = 1.f - alpha;
    float4 bv = *(const float4*)&b[cg * 4];
    float bb[4] = {bv.x, bv.y, bv.z, bv.w};
    #pragma unroll
    for (int j = 0; j < 8; ++j) {
        int row = row0 + rg * 8 + j;
        if (row < N) {
            float4 xv = *(const float4*)&X[(size_t)row * 128 + cg * 4];
            float4 ov;
            ov.x = (acc[j][0] + bb[0]) * alpha + xv.x * om;
            ov.y = (acc[j][1] + bb[1]) * alpha + xv.y * om;
            ov.z = (acc[j][2] + bb[2]) * alpha + xv.z * om;
            ov.w = (acc[j][3] + bb[3]) * alpha + xv.w * om;
            *(float4*)&O[(size_t)row * 128 + cg * 4] = ov;
        }
    }
}

extern "C" void kernel_launch(void* const* d_in, const int* in_sizes, int n_in,
                              void* d_out, int out_size, void* d_ws, size_t ws_size,
                              hipStream_t stream) {
    const float* x_a = (const float*)d_in[0];
    const float* x_b = (const float*)d_in[1];
    const int* src_ab = (const int*)d_in[2];
    const int* dst_ab = (const int*)d_in[3];
    const int* src_ba = (const int*)d_in[4];
    const int* dst_ba = (const int*)d_in[5];
    const int* src_bb = (const int*)d_in[6];
    const int* dst_bb = (const int*)d_in[7];
    const float* Wk_a = (const float*)d_in[8];  const float* bk_a = (const float*)d_in[9];
    const float* Wq_a = (const float*)d_in[10]; const float* bq_a = (const float*)d_in[11];
    const float* Wv_a = (const float*)d_in[12]; const float* bv_a = (const float*)d_in[13];
    const float* Wa_a = (const float*)d_in[14]; const float* ba_a = (const float*)d_in[15];
    const float* skip_a = (const float*)d_in[16];
    const float* Wk_b = (const float*)d_in[17]; const float* bk_b = (const float*)d_in[18];
    const float* Wq_b = (const float*)d_in[19]; const float* bq_b = (const float*)d_in[20];
    const float* Wv_b = (const float*)d_in[21]; const float* bv_b = (const float*)d_in[22];
    const float* Wa_b = (const float*)d_in[23]; const float* ba_b = (const float*)d_in[24];
    const float* skip_b = (const float*)d_in[25];
    const float* pri_ab = (const float*)d_in[26];
    const float* att_ab = (const float*)d_in[27];
    const float* msg_ab = (const float*)d_in[28];
    const float* pri_ba = (const float*)d_in[29];
    const float* att_ba = (const float*)d_in[30];
    const float* msg_ba = (const float*)d_in[31];
    const float* pri_bb = (const float*)d_in[32];
    const float* att_bb = (const float*)d_in[33];
    const float* msg_bb = (const float*)d_in[34];

    const int n_a = in_sizes[0] / D;
    const int n_b = in_sizes[1] / D;
    const int E = in_sizes[2];
    const int nmax = (n_a > n_b) ? n_a : n_b;

    size_t off = 0;
    char* base = (char*)d_ws;
    auto alloc = [&](size_t bytes) -> void* {
        void* r = base + off;
        off += (bytes + 255) & ~(size_t)255;
        return r;
    };
    unsigned short* k_a = (unsigned short*)alloc((size_t)n_a * D * 2);
    unsigned short* q_a = (unsigned short*)alloc((size_t)n_a * D * 2);
    unsigned short* v_a = (unsigned short*)alloc((size_t)n_a * D * 2);
    unsigned short* k_b = (unsigned short*)alloc((size_t)n_b * D * 2);
    unsigned short* q_b = (unsigned short*)alloc((size_t)n_b * D * 2);
    unsigned short* v_b = (unsigned short*)alloc((size_t)n_b * D * 2);
    unsigned short* qhat = (unsigned short*)alloc((size_t)nmax * D * 2);
    unsigned short* vhat = (unsigned short*)alloc((size_t)nmax * D * 2);
    float* t_a  = (float*)alloc((size_t)n_a * D * 4);
    float* t_b1 = (float*)alloc((size_t)n_b * D * 4);
    float* t_b2 = (float*)alloc((size_t)n_b * D * 4);
    int* cnt    = (int*)alloc((size_t)nmax * 4);
    int* offs   = (int*)alloc(((size_t)nmax + 1) * 4);
    int* cursor = (int*)alloc((size_t)nmax * 4);
    int* csr_src= (int*)alloc((size_t)E * 4);
    int* bsum   = (int*)alloc(256 * 4);

    const int gb_a = (n_a + 63) / 64;
    const int gb_b = (n_b + 63) / 64;
    const int gt_a = (n_a * H + 255) / 256;
    const int gt_b = (n_b * H + 255) / 256;
    const int ge   = (E + 255) / 256;

    // K/Q/V projections
    proj3_kernel<<<gb_a, 256, 0, stream>>>(x_a, Wk_a, bk_a, k_a, Wq_a, bq_a, q_a, Wv_a, bv_a, v_a, n_a);
    proj3_kernel<<<gb_b, 256, 0, stream>>>(x_b, Wk_b, bk_b, k_b, Wq_b, bq_b, q_b, Wv_b, bv_b, v_b, n_b);

    auto run_etype = [&](const int* src, const int* dst, int n_dst,
                         const unsigned short* K, const unsigned short* Q, const unsigned short* V,
                         const float* att, const float* msg, const float* pri,
                         float* T, int gt_dst, int gt_src, int n_src) {
        // CSR build
        hipMemsetAsync(cnt, 0, (size_t)n_dst * 4, stream);
        hist_kernel<<<ge, 256, 0, stream>>>(dst, cnt, E);
        int nb = (n_dst + SCAN_TILE - 1) / SCAN_TILE;
        scan1_kernel<<<nb, SCAN_BLK, 0, stream>>>(cnt, bsum, n_dst);
        scan2_kernel<<<1, 64, 0, stream>>>(bsum, nb);
        scan3_kernel<<<nb, SCAN_BLK, 0, stream>>>(cnt, bsum, offs, cursor, n_dst);
        scatter_kernel<<<ge, 256, 0, stream>>>(src, dst, cursor, csr_src, E);
        // node transforms
        node_transform_kernel<0><<<gt_dst, 256, 0, stream>>>(Q, att, qhat, n_dst);
        node_transform_kernel<1><<<gt_src, 256, 0, stream>>>(V, msg, vhat, n_src);
        // fused softmax + aggregate
        int ga = (n_dst * H + 255) / 256;
        csr_agg_kernel<<<ga, 256, 0, stream>>>(offs, csr_src, K, qhat, vhat, pri, T, n_dst);
    };

    // etype ab: src a -> dst b
    run_etype(src_ab, dst_ab, n_b, k_a, q_b, v_a, att_ab, msg_ab, pri_ab, t_b1, gt_b, gt_a, n_a);
    // etype bb: src b -> dst b
    run_etype(src_bb, dst_bb, n_b, k_b, q_b, v_b, att_bb, msg_bb, pri_bb, t_b2, gt_b, gt_b, n_b);
    // etype ba: src b -> dst a
    run_etype(src_ba, dst_ba, n_a, k_b, q_a, v_b, att_ba, msg_ba, pri_ba, t_a, gt_a, gt_b, n_b);

    // final skip-connection GEMMs
    float* out_a = (float*)d_out;
    float* out_b = (float*)d_out + (size_t)n_a * D;
    out_gemm_kernel<1><<<gb_a, 256, 0, stream>>>(t_a, nullptr, Wa_a, ba_a, skip_a, x_a, out_a, n_a);
    out_gemm_kernel<2><<<gb_b, 256, 0, stream>>>(t_b1, t_b2, Wa_b, ba_b, skip_b, x_b, out_b, n_b);
}

// Round 3
// 608.457 us; speedup vs baseline: 15.9289x; 1.9784x over previous
//
#include <hip/hip_runtime.h>
#include <hip/hip_bf16.h>
#include <stdint.h>

#define D 128
#define H 8
#define DK 16

#define SCAN_BLK 256
#define SCAN_ITEMS 8
#define SCAN_TILE (SCAN_BLK * SCAN_ITEMS)

typedef __attribute__((ext_vector_type(8))) short bf16x8;
typedef __attribute__((ext_vector_type(4))) float f32x4;

// ---------- bf16 helpers ----------
__device__ __forceinline__ unsigned short f2bf(float f) {
    unsigned int u = __float_as_uint(f);
    u = u + 0x7fffu + ((u >> 16) & 1u);      // round-to-nearest-even
    return (unsigned short)(u >> 16);
}
__device__ __forceinline__ float bfl(unsigned int u) { return __uint_as_float(u << 16); }
__device__ __forceinline__ float bfh(unsigned int u) { return __uint_as_float(u & 0xffff0000u); }
__device__ __forceinline__ unsigned int pack2(unsigned short a, unsigned short b) {
    return (unsigned int)a | ((unsigned int)b << 16);
}
__device__ __forceinline__ void unpack8(uint4 u, float* o) {
    o[0]=bfl(u.x); o[1]=bfh(u.x); o[2]=bfl(u.y); o[3]=bfh(u.y);
    o[4]=bfl(u.z); o[5]=bfh(u.z); o[6]=bfl(u.w); o[7]=bfh(u.w);
}

// ---------- W^T prep: 8 matrices [128k][128c] fp32 -> [128c][128k] bf16 ----------
struct WTIn  { const float* w[8]; };
struct WTOut { unsigned short* wt[8]; };

__global__ __launch_bounds__(256) void wt_prep_kernel(WTIn in, WTOut out) {
    __shared__ float tile[32][33];
    int mat = blockIdx.x >> 4;
    int t = blockIdx.x & 15;
    int k0 = (t >> 2) * 32, c0 = (t & 3) * 32;
    const float* W = in.w[mat];
    unsigned short* WT = out.wt[mat];
    int tid = threadIdx.x;
    int lr = tid >> 5, lc = tid & 31;
    #pragma unroll
    for (int p = 0; p < 4; ++p)
        tile[p * 8 + lr][lc] = W[(size_t)(k0 + p * 8 + lr) * D + c0 + lc];
    __syncthreads();
    #pragma unroll
    for (int p = 0; p < 4; ++p)
        WT[(size_t)(c0 + p * 8 + lr) * D + k0 + lc] = f2bf(tile[lc][p * 8 + lr]);
}

// ---------- MFMA projection: O_m = bf16(x @ W_m + b_m), m in {k,q,v} ----------
// 256 thr = 4 waves; block does 64 rows x 128 cols; wave w does 64x32 (cols w*32..).
#define ASTRIDE 136
__global__ __launch_bounds__(256) void mfma_proj3_kernel(
    const float* __restrict__ X,
    const unsigned short* __restrict__ WT0, const float* __restrict__ b0, unsigned short* __restrict__ O0,
    const unsigned short* __restrict__ WT1, const float* __restrict__ b1, unsigned short* __restrict__ O1,
    const unsigned short* __restrict__ WT2, const float* __restrict__ b2, unsigned short* __restrict__ O2,
    int N)
{
    __shared__ unsigned short As[64 * ASTRIDE];   // [row][k], 272B row stride (2-way bank alias only)
    const int tid = threadIdx.x;
    const int w = tid >> 6;
    const int l = tid & 63;
    const int row0 = blockIdx.x * 64;

    // stage A tile: 64x128 fp32 -> bf16 LDS (shared by all 3 GEMMs)
    #pragma unroll
    for (int p = 0; p < 8; ++p) {
        int f = p * 256 + tid;            // float4 index
        int r = f >> 5;
        int c4 = f & 31;
        int row = row0 + r; if (row >= N) row = N - 1;
        float4 xv = *(const float4*)&X[(size_t)row * D + c4 * 4];
        unsigned int lo = pack2(f2bf(xv.x), f2bf(xv.y));
        unsigned int hi = pack2(f2bf(xv.z), f2bf(xv.w));
        *(uint2*)&As[r * ASTRIDE + c4 * 4] = make_uint2(lo, hi);
    }
    __syncthreads();

    const int lrow = l & 15;
    const int lk8 = (l >> 4) * 8;

    const unsigned short* WTs[3] = {WT0, WT1, WT2};
    const float* bs[3] = {b0, b1, b2};
    unsigned short* Os[3] = {O0, O1, O2};

    #pragma unroll 1
    for (int m = 0; m < 3; ++m) {
        const unsigned short* WT = WTs[m];
        bf16x8 bfrag[2][4];
        #pragma unroll
        for (int cf = 0; cf < 2; ++cf)
            #pragma unroll
            for (int kc = 0; kc < 4; ++kc)
                bfrag[cf][kc] = *(const bf16x8*)&WT[(size_t)(w * 32 + cf * 16 + lrow) * D + kc * 32 + lk8];

        f32x4 acc[4][2];
        #pragma unroll
        for (int rf = 0; rf < 4; ++rf) {
            acc[rf][0] = (f32x4){0.f, 0.f, 0.f, 0.f};
            acc[rf][1] = (f32x4){0.f, 0.f, 0.f, 0.f};
        }
        #pragma unroll
        for (int rf = 0; rf < 4; ++rf) {
            bf16x8 afrag[4];
            #pragma unroll
            for (int kc = 0; kc < 4; ++kc)
                afrag[kc] = *(const bf16x8*)&As[(rf * 16 + lrow) * ASTRIDE + kc * 32 + lk8];
            #pragma unroll
            for (int kc = 0; kc < 4; ++kc) {
                acc[rf][0] = __builtin_amdgcn_mfma_f32_16x16x32_bf16(afrag[kc], bfrag[0][kc], acc[rf][0], 0, 0, 0);
                acc[rf][1] = __builtin_amdgcn_mfma_f32_16x16x32_bf16(afrag[kc], bfrag[1][kc], acc[rf][1], 0, 0, 0);
            }
        }
        float bias0 = bs[m][w * 32 + lrow];
        float bias1 = bs[m][w * 32 + 16 + lrow];
        unsigned short* O = Os[m];
        #pragma unroll
        for (int rf = 0; rf < 4; ++rf) {
            #pragma unroll
            for (int r = 0; r < 4; ++r) {
                int row = row0 + rf * 16 + (l >> 4) * 4 + r;
                if (row < N) {
                    O[(size_t)row * D + w * 32 + lrow]      = f2bf(acc[rf][0][r] + bias0);
                    O[(size_t)row * D + w * 32 + 16 + lrow] = f2bf(acc[rf][1][r] + bias1);
                }
            }
        }
    }
}

// ---------- MFMA out-GEMM: O = (relu-comb(T) @ Wa + b)*alpha + X*(1-alpha), fp32 out ----------
template<int NSRC>
__global__ __launch_bounds__(256) void out_gemm_mfma_kernel(
    const float* __restrict__ T1, const float* __restrict__ T2,
    const unsigned short* __restrict__ WT, const float* __restrict__ b,
    const float* __restrict__ skip, const float* __restrict__ X,
    float* __restrict__ O, int N)
{
    __shared__ unsigned short As[64 * ASTRIDE];
    const int tid = threadIdx.x;
    const int w = tid >> 6;
    const int l = tid & 63;
    const int row0 = blockIdx.x * 64;

    #pragma unroll
    for (int p = 0; p < 8; ++p) {
        int f = p * 256 + tid;
        int r = f >> 5;
        int c4 = f & 31;
        int row = row0 + r; if (row >= N) row = N - 1;
        float4 tv = *(const float4*)&T1[(size_t)row * D + c4 * 4];
        float v0 = fmaxf(tv.x, 0.f), v1 = fmaxf(tv.y, 0.f), v2 = fmaxf(tv.z, 0.f), v3 = fmaxf(tv.w, 0.f);
        if (NSRC == 2) {
            float4 uv = *(const float4*)&T2[(size_t)row * D + c4 * 4];
            v0 = 0.5f * (v0 + fmaxf(uv.x, 0.f));
            v1 = 0.5f * (v1 + fmaxf(uv.y, 0.f));
            v2 = 0.5f * (v2 + fmaxf(uv.z, 0.f));
            v3 = 0.5f * (v3 + fmaxf(uv.w, 0.f));
        }
        unsigned int lo = pack2(f2bf(v0), f2bf(v1));
        unsigned int hi = pack2(f2bf(v2), f2bf(v3));
        *(uint2*)&As[r * ASTRIDE + c4 * 4] = make_uint2(lo, hi);
    }
    __syncthreads();

    const int lrow = l & 15;
    const int lk8 = (l >> 4) * 8;

    bf16x8 bfrag[2][4];
    #pragma unroll
    for (int cf = 0; cf < 2; ++cf)
        #pragma unroll
        for (int kc = 0; kc < 4; ++kc)
            bfrag[cf][kc] = *(const bf16x8*)&WT[(size_t)(w * 32 + cf * 16 + lrow) * D + kc * 32 + lk8];

    f32x4 acc[4][2];
    #pragma unroll
    for (int rf = 0; rf < 4; ++rf) {
        acc[rf][0] = (f32x4){0.f, 0.f, 0.f, 0.f};
        acc[rf][1] = (f32x4){0.f, 0.f, 0.f, 0.f};
    }
    #pragma unroll
    for (int rf = 0; rf < 4; ++rf) {
        bf16x8 afrag[4];
        #pragma unroll
        for (int kc = 0; kc < 4; ++kc)
            afrag[kc] = *(const bf16x8*)&As[(rf * 16 + lrow) * ASTRIDE + kc * 32 + lk8];
        #pragma unroll
        for (int kc = 0; kc < 4; ++kc) {
            acc[rf][0] = __builtin_amdgcn_mfma_f32_16x16x32_bf16(afrag[kc], bfrag[0][kc], acc[rf][0], 0, 0, 0);
            acc[rf][1] = __builtin_amdgcn_mfma_f32_16x16x32_bf16(afrag[kc], bfrag[1][kc], acc[rf][1], 0, 0, 0);
        }
    }
    float alpha = 1.f / (1.f + __expf(-skip[0]));
    float om = 1.f - alpha;
    float bias0 = b[w * 32 + lrow];
    float bias1 = b[w * 32 + 16 + lrow];
    #pragma unroll
    for (int rf = 0; rf < 4; ++rf) {
        #pragma unroll
        for (int r = 0; r < 4; ++r) {
            int row = row0 + rf * 16 + (l >> 4) * 4 + r;
            if (row < N) {
                int c0 = w * 32 + lrow;
                float x0 = X[(size_t)row * D + c0];
                float x1 = X[(size_t)row * D + c0 + 16];
                O[(size_t)row * D + c0]      = (acc[rf][0][r] + bias0) * alpha + x0 * om;
                O[(size_t)row * D + c0 + 16] = (acc[rf][1][r] + bias1) * alpha + x1 * om;
            }
        }
    }
}

// ---------- per-node 16x16 head transform ----------
template<int MODE>
__global__ __launch_bounds__(256) void node_transform_kernel(
    const unsigned short* __restrict__ IN, const float* __restrict__ R,
    unsigned short* __restrict__ OUT, int N)
{
    __shared__ float Rl[H * 257];
    const int tid = threadIdx.x;
    #pragma unroll
    for (int i = 0; i < 8; ++i) {
        int idx = i * 256 + tid;
        Rl[(idx >> 8) * 257 + (idx & 255)] = R[idx];
    }
    __syncthreads();
    int gid = blockIdx.x * 256 + tid;
    int n = gid >> 3, h = gid & 7;
    if (n >= N) return;
    const uint4* ip = (const uint4*)(IN + (size_t)n * D + h * DK);
    uint4 i0 = ip[0], i1 = ip[1];
    float inv[16];
    unpack8(i0, inv); unpack8(i1, inv + 8);
    const float* Rh = &Rl[h * 257];
    unsigned short ob[16];
    #pragma unroll
    for (int d = 0; d < 16; ++d) {
        float s = 0.f;
        #pragma unroll
        for (int f = 0; f < 16; ++f) {
            float r = (MODE == 0) ? Rh[d * 16 + f] : Rh[f * 16 + d];
            s = fmaf(r, inv[f], s);
        }
        ob[d] = f2bf(s);
    }
    uint4 o0, o1;
    o0.x = pack2(ob[0], ob[1]);  o0.y = pack2(ob[2], ob[3]);
    o0.z = pack2(ob[4], ob[5]);  o0.w = pack2(ob[6], ob[7]);
    o1.x = pack2(ob[8], ob[9]);  o1.y = pack2(ob[10], ob[11]);
    o1.z = pack2(ob[12], ob[13]); o1.w = pack2(ob[14], ob[15]);
    uint4* op = (uint4*)(OUT + (size_t)n * D + h * DK);
    op[0] = o0; op[1] = o1;
}

// ---------- CSR build: histogram -> scan -> scatter ----------
__global__ __launch_bounds__(256) void hist_kernel(const int* __restrict__ dst, int* __restrict__ cnt, int E) {
    int e = blockIdx.x * 256 + threadIdx.x;
    if (e < E) atomicAdd(&cnt[dst[e]], 1);
}

__global__ __launch_bounds__(SCAN_BLK) void scan1_kernel(const int* __restrict__ cnt, int* __restrict__ bsum, int n) {
    __shared__ int sh[SCAN_BLK];
    int base = blockIdx.x * SCAN_TILE + threadIdx.x * SCAN_ITEMS;
    int s = 0;
    #pragma unroll
    for (int i = 0; i < SCAN_ITEMS; ++i) {
        int idx = base + i;
        if (idx < n) s += cnt[idx];
    }
    sh[threadIdx.x] = s; __syncthreads();
    for (int o = SCAN_BLK / 2; o > 0; o >>= 1) {
        if (threadIdx.x < o) sh[threadIdx.x] += sh[threadIdx.x + o];
        __syncthreads();
    }
    if (threadIdx.x == 0) bsum[blockIdx.x] = sh[0];
}

__global__ void scan2_kernel(int* __restrict__ bsum, int nb) {
    if (threadIdx.x == 0 && blockIdx.x == 0) {
        int acc = 0;
        for (int i = 0; i < nb; ++i) { int v = bsum[i]; bsum[i] = acc; acc += v; }
    }
}

__global__ __launch_bounds__(SCAN_BLK) void scan3_kernel(
    const int* __restrict__ cnt, const int* __restrict__ bsum,
    int* __restrict__ offs, int* __restrict__ cursor, int n)
{
    __shared__ int sh[SCAN_BLK];
    int base = blockIdx.x * SCAN_TILE + threadIdx.x * SCAN_ITEMS;
    int v[SCAN_ITEMS];
    int s = 0;
    #pragma unroll
    for (int i = 0; i < SCAN_ITEMS; ++i) {
        int idx = base + i;
        v[i] = (idx < n) ? cnt[idx] : 0;
        s += v[i];
    }
    sh[threadIdx.x] = s; __syncthreads();
    for (int o = 1; o < SCAN_BLK; o <<= 1) {
        int t = (threadIdx.x >= o) ? sh[threadIdx.x - o] : 0;
        __syncthreads();
        sh[threadIdx.x] += t;
        __syncthreads();
    }
    int off = bsum[blockIdx.x] + sh[threadIdx.x] - s;
    #pragma unroll
    for (int i = 0; i < SCAN_ITEMS; ++i) {
        int idx = base + i;
        if (idx < n) {
            offs[idx] = off;
            cursor[idx] = off;
            off += v[i];
            if (idx == n - 1) offs[n] = off;
        }
    }
}

__global__ __launch_bounds__(256) void scatter_kernel(
    const int* __restrict__ src, const int* __restrict__ dst,
    int* __restrict__ cursor, int* __restrict__ csr_src, int E)
{
    int e = blockIdx.x * 256 + threadIdx.x;
    if (e < E) {
        int p = atomicAdd(&cursor[dst[e]], 1);
        csr_src[p] = src[e];
    }
}

// ---------- fused per-dst softmax + aggregate over CSR segment ----------
__global__ __launch_bounds__(256) void csr_agg_kernel(
    const int* __restrict__ offs, const int* __restrict__ csr_src,
    const unsigned short* __restrict__ K, const unsigned short* __restrict__ QH,
    const unsigned short* __restrict__ VH, const float* __restrict__ pri,
    float* __restrict__ T, int n_dst)
{
    int gid = blockIdx.x * 256 + threadIdx.x;
    int n = gid >> 3, h = gid & 7;
    if (n >= n_dst) return;
    int e0 = offs[n], e1 = offs[n + 1];

    const uint4* qp = (const uint4*)(QH + (size_t)n * D + h * DK);
    uint4 q0 = qp[0], q1 = qp[1];
    float qv[16];
    unpack8(q0, qv); unpack8(q1, qv + 8);
    float ps = pri[h] * 0.25f;

    float acc[16];
    #pragma unroll
    for (int i = 0; i < 16; ++i) acc[i] = 0.f;
    float den = 0.f;

    for (int e = e0; e < e1; ++e) {
        int s = csr_src[e];
        const uint4* kp = (const uint4*)(K + (size_t)s * D + h * DK);
        uint4 k0 = kp[0], k1 = kp[1];
        float kv[16];
        unpack8(k0, kv); unpack8(k1, kv + 8);
        float a = 0.f;
        #pragma unroll
        for (int i = 0; i < 16; ++i) a = fmaf(kv[i], qv[i], a);
        float ea = __expf(a * ps);
        den += ea;
        const uint4* vp = (const uint4*)(VH + (size_t)s * D + h * DK);
        uint4 v0 = vp[0], v1 = vp[1];
        float vv[16];
        unpack8(v0, vv); unpack8(v1, vv + 8);
        #pragma unroll
        for (int i = 0; i < 16; ++i) acc[i] = fmaf(ea, vv[i], acc[i]);
    }
    float inv = 1.f / fmaxf(den, 1e-9f);
    float* tp = T + (size_t)n * D + h * DK;
    *(float4*)(tp + 0)  = make_float4(acc[0]*inv, acc[1]*inv, acc[2]*inv, acc[3]*inv);
    *(float4*)(tp + 4)  = make_float4(acc[4]*inv, acc[5]*inv, acc[6]*inv, acc[7]*inv);
    *(float4*)(tp + 8)  = make_float4(acc[8]*inv, acc[9]*inv, acc[10]*inv, acc[11]*inv);
    *(float4*)(tp + 12) = make_float4(acc[12]*inv, acc[13]*inv, acc[14]*inv, acc[15]*inv);
}

extern "C" void kernel_launch(void* const* d_in, const int* in_sizes, int n_in,
                              void* d_out, int out_size, void* d_ws, size_t ws_size,
                              hipStream_t stream) {
    const float* x_a = (const float*)d_in[0];
    const float* x_b = (const float*)d_in[1];
    const int* src_ab = (const int*)d_in[2];
    const int* dst_ab = (const int*)d_in[3];
    const int* src_ba = (const int*)d_in[4];
    const int* dst_ba = (const int*)d_in[5];
    const int* src_bb = (const int*)d_in[6];
    const int* dst_bb = (const int*)d_in[7];
    const float* Wk_a = (const float*)d_in[8];  const float* bk_a = (const float*)d_in[9];
    const float* Wq_a = (const float*)d_in[10]; const float* bq_a = (const float*)d_in[11];
    const float* Wv_a = (const float*)d_in[12]; const float* bv_a = (const float*)d_in[13];
    const float* Wa_a = (const float*)d_in[14]; const float* ba_a = (const float*)d_in[15];
    const float* skip_a = (const float*)d_in[16];
    const float* Wk_b = (const float*)d_in[17]; const float* bk_b = (const float*)d_in[18];
    const float* Wq_b = (const float*)d_in[19]; const float* bq_b = (const float*)d_in[20];
    const float* Wv_b = (const float*)d_in[21]; const float* bv_b = (const float*)d_in[22];
    const float* Wa_b = (const float*)d_in[23]; const float* ba_b = (const float*)d_in[24];
    const float* skip_b = (const float*)d_in[25];
    const float* pri_ab = (const float*)d_in[26];
    const float* att_ab = (const float*)d_in[27];
    const float* msg_ab = (const float*)d_in[28];
    const float* pri_ba = (const float*)d_in[29];
    const float* att_ba = (const float*)d_in[30];
    const float* msg_ba = (const float*)d_in[31];
    const float* pri_bb = (const float*)d_in[32];
    const float* att_bb = (const float*)d_in[33];
    const float* msg_bb = (const float*)d_in[34];

    const int n_a = in_sizes[0] / D;
    const int n_b = in_sizes[1] / D;
    const int E = in_sizes[2];
    const int nmax = (n_a > n_b) ? n_a : n_b;

    size_t off = 0;
    char* base = (char*)d_ws;
    auto alloc = [&](size_t bytes) -> void* {
        void* r = base + off;
        off += (bytes + 255) & ~(size_t)255;
        return r;
    };
    unsigned short* k_a = (unsigned short*)alloc((size_t)n_a * D * 2);
    unsigned short* q_a = (unsigned short*)alloc((size_t)n_a * D * 2);
    unsigned short* v_a = (unsigned short*)alloc((size_t)n_a * D * 2);
    unsigned short* k_b = (unsigned short*)alloc((size_t)n_b * D * 2);
    unsigned short* q_b = (unsigned short*)alloc((size_t)n_b * D * 2);
    unsigned short* v_b = (unsigned short*)alloc((size_t)n_b * D * 2);
    unsigned short* qhat = (unsigned short*)alloc((size_t)nmax * D * 2);
    unsigned short* vhat = (unsigned short*)alloc((size_t)nmax * D * 2);
    float* t_a  = (float*)alloc((size_t)n_a * D * 4);
    float* t_b1 = (float*)alloc((size_t)n_b * D * 4);
    float* t_b2 = (float*)alloc((size_t)n_b * D * 4);
    int* cnt    = (int*)alloc((size_t)nmax * 4);
    int* offs   = (int*)alloc(((size_t)nmax + 1) * 4);
    int* cursor = (int*)alloc((size_t)nmax * 4);
    int* csr_src= (int*)alloc((size_t)E * 4);
    int* bsum   = (int*)alloc(256 * 4);
    unsigned short* wts[8];
    for (int i = 0; i < 8; ++i) wts[i] = (unsigned short*)alloc((size_t)D * D * 2);

    const int gb_a = (n_a + 63) / 64;
    const int gb_b = (n_b + 63) / 64;
    const int gt_a = (n_a * H + 255) / 256;
    const int gt_b = (n_b * H + 255) / 256;
    const int ge   = (E + 255) / 256;

    // W^T bf16 prep for all 8 weight matrices
    WTIn win; WTOut wout;
    const float* worig[8] = {Wk_a, Wq_a, Wv_a, Wa_a, Wk_b, Wq_b, Wv_b, Wa_b};
    for (int i = 0; i < 8; ++i) { win.w[i] = worig[i]; wout.wt[i] = wts[i]; }
    wt_prep_kernel<<<128, 256, 0, stream>>>(win, wout);

    // K/Q/V projections (MFMA)
    mfma_proj3_kernel<<<gb_a, 256, 0, stream>>>(x_a, wts[0], bk_a, k_a, wts[1], bq_a, q_a, wts[2], bv_a, v_a, n_a);
    mfma_proj3_kernel<<<gb_b, 256, 0, stream>>>(x_b, wts[4], bk_b, k_b, wts[5], bq_b, q_b, wts[6], bv_b, v_b, n_b);

    auto run_etype = [&](const int* src, const int* dst, int n_dst,
                         const unsigned short* K, const unsigned short* Q, const unsigned short* V,
                         const float* att, const float* msg, const float* pri,
                         float* T, int gt_dst, int gt_src, int n_src) {
        hipMemsetAsync(cnt, 0, (size_t)n_dst * 4, stream);
        hist_kernel<<<ge, 256, 0, stream>>>(dst, cnt, E);
        int nb = (n_dst + SCAN_TILE - 1) / SCAN_TILE;
        scan1_kernel<<<nb, SCAN_BLK, 0, stream>>>(cnt, bsum, n_dst);
        scan2_kernel<<<1, 64, 0, stream>>>(bsum, nb);
        scan3_kernel<<<nb, SCAN_BLK, 0, stream>>>(cnt, bsum, offs, cursor, n_dst);
        scatter_kernel<<<ge, 256, 0, stream>>>(src, dst, cursor, csr_src, E);
        node_transform_kernel<0><<<gt_dst, 256, 0, stream>>>(Q, att, qhat, n_dst);
        node_transform_kernel<1><<<gt_src, 256, 0, stream>>>(V, msg, vhat, n_src);
        int ga = (n_dst * H + 255) / 256;
        csr_agg_kernel<<<ga, 256, 0, stream>>>(offs, csr_src, K, qhat, vhat, pri, T, n_dst);
    };

    run_etype(src_ab, dst_ab, n_b, k_a, q_b, v_a, att_ab, msg_ab, pri_ab, t_b1, gt_b, gt_a, n_a);
    run_etype(src_bb, dst_bb, n_b, k_b, q_b, v_b, att_bb, msg_bb, pri_bb, t_b2, gt_b, gt_b, n_b);
    run_etype(src_ba, dst_ba, n_a, k_b, q_a, v_b, att_ba, msg_ba, pri_ba, t_a, gt_a, gt_b, n_b);

    // final skip-connection GEMMs (MFMA)
    float* out_a = (float*)d_out;
    float* out_b = (float*)d_out + (size_t)n_a * D;
    out_gemm_mfma_kernel<1><<<gb_a, 256, 0, stream>>>(t_a, nullptr, wts[3], ba_a, skip_a, x_a, out_a, n_a);
    out_gemm_mfma_kernel<2><<<gb_b, 256, 0, stream>>>(t_b1, t_b2, wts[7], ba_b, skip_b, x_b, out_b, n_b);
}

// Round 4
// 493.225 us; speedup vs baseline: 19.6504x; 1.2336x over previous
//
#include <hip/hip_runtime.h>
#include <hip/hip_bf16.h>
#include <stdint.h>

#define D 128
#define H 8
#define DK 16

#define SCAN_BLK 256
#define SCAN_ITEMS 8
#define SCAN_TILE (SCAN_BLK * SCAN_ITEMS)

typedef __attribute__((ext_vector_type(8))) short bf16x8;
typedef __attribute__((ext_vector_type(4))) float f32x4;

// ---------- bf16 helpers ----------
__device__ __forceinline__ unsigned short f2bf(float f) {
    unsigned int u = __float_as_uint(f);
    u = u + 0x7fffu + ((u >> 16) & 1u);      // round-to-nearest-even
    return (unsigned short)(u >> 16);
}
__device__ __forceinline__ float bfl(unsigned int u) { return __uint_as_float(u << 16); }
__device__ __forceinline__ float bfh(unsigned int u) { return __uint_as_float(u & 0xffff0000u); }
__device__ __forceinline__ unsigned int pack2(unsigned short a, unsigned short b) {
    return (unsigned int)a | ((unsigned int)b << 16);
}
__device__ __forceinline__ void unpack8(uint4 u, float* o) {
    o[0]=bfl(u.x); o[1]=bfh(u.x); o[2]=bfl(u.y); o[3]=bfh(u.y);
    o[4]=bfl(u.z); o[5]=bfh(u.z); o[6]=bfl(u.w); o[7]=bfh(u.w);
}

// ---------- plain W^T prep: 4 matrices [128k][128c] fp32 -> [128c][128k] bf16 ----------
struct WTIn  { const float* w[4]; };
struct WTOut { unsigned short* wt[4]; };

__global__ __launch_bounds__(256) void wt_prep_kernel(WTIn in, WTOut out) {
    __shared__ float tile[32][33];
    int mat = blockIdx.x >> 4;
    int t = blockIdx.x & 15;
    int k0 = (t >> 2) * 32, c0 = (t & 3) * 32;
    const float* W = in.w[mat];
    unsigned short* WT = out.wt[mat];
    int tid = threadIdx.x;
    int lr = tid >> 5, lc = tid & 31;
    #pragma unroll
    for (int p = 0; p < 4; ++p)
        tile[p * 8 + lr][lc] = W[(size_t)(k0 + p * 8 + lr) * D + c0 + lc];
    __syncthreads();
    #pragma unroll
    for (int p = 0; p < 4; ++p)
        WT[(size_t)(c0 + p * 8 + lr) * D + k0 + lc] = f2bf(tile[lc][p * 8 + lr]);
}

// ---------- fold relation matrices into projection weights ----------
// mode 0 (q/att):  WT'[h*16+j][c] = sum_i W[c][h*16+i] * R[h][j][i]
// mode 1 (v/msg):  WT'[h*16+j][c] = sum_i W[c][h*16+i] * R[h][i][j]
// bias folds likewise. One block per (variant, head).
struct FoldArgs {
    const float* W[6]; const float* R[6]; const float* b[6];
    unsigned short* WT[6]; float* bf[6]; int mode[6];
};
__global__ __launch_bounds__(256) void fold_kernel(FoldArgs a) {
    __shared__ float Wl[128 * 17];
    __shared__ float Rl[256];
    int v = blockIdx.x >> 3, h = blockIdx.x & 7;
    const float* W = a.W[v];
    int tid = threadIdx.x;
    #pragma unroll
    for (int p = 0; p < 8; ++p) {
        int idx = p * 256 + tid;
        int c = idx >> 4, i = idx & 15;
        Wl[c * 17 + i] = W[(size_t)c * D + h * 16 + i];
    }
    Rl[tid] = a.R[v][h * 256 + tid];
    __syncthreads();
    int mode = a.mode[v];
    int c = tid & 127, jb = (tid >> 7) * 8;
    #pragma unroll
    for (int jj = 0; jj < 8; ++jj) {
        int j = jb + jj;
        float s = 0.f;
        #pragma unroll
        for (int i = 0; i < 16; ++i)
            s = fmaf(Wl[c * 17 + i], mode ? Rl[i * 16 + j] : Rl[j * 16 + i], s);
        a.WT[v][(size_t)(h * 16 + j) * D + c] = f2bf(s);
    }
    if (tid < 16) {
        const float* b = a.b[v];
        float s = 0.f;
        #pragma unroll
        for (int i = 0; i < 16; ++i)
            s = fmaf(b[h * 16 + i], mode ? Rl[i * 16 + tid] : Rl[tid * 16 + i], s);
        a.bf[v][h * 16 + tid] = s;
    }
}

// ---------- MFMA multi-output projection: OUT[m] = bf16(x @ W'[m] + b'[m]) ----------
#define ASTRIDE 136
template<int NMAT> struct ProjArgs {
    const unsigned short* wt[NMAT];
    const float* bias[NMAT];
    unsigned short* out[NMAT];
};

template<int NMAT>
__global__ __launch_bounds__(256, 2) void proj_all_kernel(
    const float* __restrict__ X, ProjArgs<NMAT> a, int N)
{
    __shared__ unsigned short As[64 * ASTRIDE];
    const int tid = threadIdx.x;
    const int w = tid >> 6;
    const int l = tid & 63;
    const int row0 = blockIdx.x * 64;

    #pragma unroll
    for (int p = 0; p < 8; ++p) {
        int f = p * 256 + tid;
        int r = f >> 5;
        int c4 = f & 31;
        int row = row0 + r; if (row >= N) row = N - 1;
        float4 xv = *(const float4*)&X[(size_t)row * D + c4 * 4];
        unsigned int lo = pack2(f2bf(xv.x), f2bf(xv.y));
        unsigned int hi = pack2(f2bf(xv.z), f2bf(xv.w));
        *(uint2*)&As[r * ASTRIDE + c4 * 4] = make_uint2(lo, hi);
    }
    __syncthreads();

    const int lrow = l & 15;
    const int lk8 = (l >> 4) * 8;

    #pragma unroll
    for (int m = 0; m < NMAT; ++m) {
        const unsigned short* WT = a.wt[m];
        bf16x8 bfrag[2][4];
        #pragma unroll
        for (int cf = 0; cf < 2; ++cf)
            #pragma unroll
            for (int kc = 0; kc < 4; ++kc)
                bfrag[cf][kc] = *(const bf16x8*)&WT[(size_t)(w * 32 + cf * 16 + lrow) * D + kc * 32 + lk8];

        f32x4 acc[4][2];
        #pragma unroll
        for (int rf = 0; rf < 4; ++rf) {
            acc[rf][0] = (f32x4){0.f, 0.f, 0.f, 0.f};
            acc[rf][1] = (f32x4){0.f, 0.f, 0.f, 0.f};
        }
        #pragma unroll
        for (int rf = 0; rf < 4; ++rf) {
            bf16x8 afrag[4];
            #pragma unroll
            for (int kc = 0; kc < 4; ++kc)
                afrag[kc] = *(const bf16x8*)&As[(rf * 16 + lrow) * ASTRIDE + kc * 32 + lk8];
            #pragma unroll
            for (int kc = 0; kc < 4; ++kc) {
                acc[rf][0] = __builtin_amdgcn_mfma_f32_16x16x32_bf16(afrag[kc], bfrag[0][kc], acc[rf][0], 0, 0, 0);
                acc[rf][1] = __builtin_amdgcn_mfma_f32_16x16x32_bf16(afrag[kc], bfrag[1][kc], acc[rf][1], 0, 0, 0);
            }
        }
        float bias0 = a.bias[m][w * 32 + lrow];
        float bias1 = a.bias[m][w * 32 + 16 + lrow];
        unsigned short* O = a.out[m];
        #pragma unroll
        for (int rf = 0; rf < 4; ++rf) {
            #pragma unroll
            for (int r = 0; r < 4; ++r) {
                int row = row0 + rf * 16 + (l >> 4) * 4 + r;
                if (row < N) {
                    O[(size_t)row * D + w * 32 + lrow]      = f2bf(acc[rf][0][r] + bias0);
                    O[(size_t)row * D + w * 32 + 16 + lrow] = f2bf(acc[rf][1][r] + bias1);
                }
            }
        }
    }
}

// ---------- MFMA out-GEMM: O = (relu-comb(T) @ Wa + b)*alpha + X*(1-alpha), fp32 out ----------
template<int NSRC>
__global__ __launch_bounds__(256) void out_gemm_mfma_kernel(
    const unsigned short* __restrict__ T1, const unsigned short* __restrict__ T2,
    const unsigned short* __restrict__ WT, const float* __restrict__ b,
    const float* __restrict__ skip, const float* __restrict__ X,
    float* __restrict__ O, int N)
{
    __shared__ unsigned short As[64 * ASTRIDE];
    const int tid = threadIdx.x;
    const int w = tid >> 6;
    const int l = tid & 63;
    const int row0 = blockIdx.x * 64;

    #pragma unroll
    for (int p = 0; p < 4; ++p) {
        int idx = p * 256 + tid;
        int r = idx >> 4;
        int c8 = idx & 15;
        int row = row0 + r; if (row >= N) row = N - 1;
        uint4 tv = *(const uint4*)&T1[(size_t)row * D + c8 * 8];
        float v[8]; unpack8(tv, v);
        #pragma unroll
        for (int i = 0; i < 8; ++i) v[i] = fmaxf(v[i], 0.f);
        if (NSRC == 2) {
            uint4 uv = *(const uint4*)&T2[(size_t)row * D + c8 * 8];
            float u[8]; unpack8(uv, u);
            #pragma unroll
            for (int i = 0; i < 8; ++i) v[i] = 0.5f * (v[i] + fmaxf(u[i], 0.f));
        }
        uint4 pk;
        pk.x = pack2(f2bf(v[0]), f2bf(v[1]));
        pk.y = pack2(f2bf(v[2]), f2bf(v[3]));
        pk.z = pack2(f2bf(v[4]), f2bf(v[5]));
        pk.w = pack2(f2bf(v[6]), f2bf(v[7]));
        *(uint4*)&As[r * ASTRIDE + c8 * 8] = pk;
    }
    __syncthreads();

    const int lrow = l & 15;
    const int lk8 = (l >> 4) * 8;

    bf16x8 bfrag[2][4];
    #pragma unroll
    for (int cf = 0; cf < 2; ++cf)
        #pragma unroll
        for (int kc = 0; kc < 4; ++kc)
            bfrag[cf][kc] = *(const bf16x8*)&WT[(size_t)(w * 32 + cf * 16 + lrow) * D + kc * 32 + lk8];

    f32x4 acc[4][2];
    #pragma unroll
    for (int rf = 0; rf < 4; ++rf) {
        acc[rf][0] = (f32x4){0.f, 0.f, 0.f, 0.f};
        acc[rf][1] = (f32x4){0.f, 0.f, 0.f, 0.f};
    }
    #pragma unroll
    for (int rf = 0; rf < 4; ++rf) {
        bf16x8 afrag[4];
        #pragma unroll
        for (int kc = 0; kc < 4; ++kc)
            afrag[kc] = *(const bf16x8*)&As[(rf * 16 + lrow) * ASTRIDE + kc * 32 + lk8];
        #pragma unroll
        for (int kc = 0; kc < 4; ++kc) {
            acc[rf][0] = __builtin_amdgcn_mfma_f32_16x16x32_bf16(afrag[kc], bfrag[0][kc], acc[rf][0], 0, 0, 0);
            acc[rf][1] = __builtin_amdgcn_mfma_f32_16x16x32_bf16(afrag[kc], bfrag[1][kc], acc[rf][1], 0, 0, 0);
        }
    }
    float alpha = 1.f / (1.f + __expf(-skip[0]));
    float om = 1.f - alpha;
    float bias0 = b[w * 32 + lrow];
    float bias1 = b[w * 32 + 16 + lrow];
    #pragma unroll
    for (int rf = 0; rf < 4; ++rf) {
        #pragma unroll
        for (int r = 0; r < 4; ++r) {
            int row = row0 + rf * 16 + (l >> 4) * 4 + r;
            if (row < N) {
                int c0 = w * 32 + lrow;
                float x0 = X[(size_t)row * D + c0];
                float x1 = X[(size_t)row * D + c0 + 16];
                O[(size_t)row * D + c0]      = (acc[rf][0][r] + bias0) * alpha + x0 * om;
                O[(size_t)row * D + c0 + 16] = (acc[rf][1][r] + bias1) * alpha + x1 * om;
            }
        }
    }
}

// ---------- combined CSR build over 3 etypes in slot space ----------
struct EdgeArgs {
    const int* src[3]; const int* dst[3]; int base[3]; int E;
};

__global__ __launch_bounds__(256) void hist_all_kernel(EdgeArgs a, int* __restrict__ cnt) {
    int gid = blockIdx.x * 256 + threadIdx.x;
    int E = a.E;
    if (gid >= 3 * E) return;
    int t = (gid < E) ? 0 : ((gid < 2 * E) ? 1 : 2);
    int e = gid - t * E;
    atomicAdd(&cnt[a.base[t] + a.dst[t][e]], 1);
}

__global__ __launch_bounds__(SCAN_BLK) void scan1_kernel(const int* __restrict__ cnt, int* __restrict__ bsum, int n) {
    __shared__ int sh[SCAN_BLK];
    int base = blockIdx.x * SCAN_TILE + threadIdx.x * SCAN_ITEMS;
    int s = 0;
    #pragma unroll
    for (int i = 0; i < SCAN_ITEMS; ++i) {
        int idx = base + i;
        if (idx < n) s += cnt[idx];
    }
    sh[threadIdx.x] = s; __syncthreads();
    for (int o = SCAN_BLK / 2; o > 0; o >>= 1) {
        if (threadIdx.x < o) sh[threadIdx.x] += sh[threadIdx.x + o];
        __syncthreads();
    }
    if (threadIdx.x == 0) bsum[blockIdx.x] = sh[0];
}

__global__ void scan2_kernel(int* __restrict__ bsum, int nb) {
    if (threadIdx.x == 0 && blockIdx.x == 0) {
        int acc = 0;
        for (int i = 0; i < nb; ++i) { int v = bsum[i]; bsum[i] = acc; acc += v; }
    }
}

__global__ __launch_bounds__(SCAN_BLK) void scan3_kernel(
    const int* __restrict__ cnt, const int* __restrict__ bsum,
    int* __restrict__ offs, int* __restrict__ cursor, int n)
{
    __shared__ int sh[SCAN_BLK];
    int base = blockIdx.x * SCAN_TILE + threadIdx.x * SCAN_ITEMS;
    int v[SCAN_ITEMS];
    int s = 0;
    #pragma unroll
    for (int i = 0; i < SCAN_ITEMS; ++i) {
        int idx = base + i;
        v[i] = (idx < n) ? cnt[idx] : 0;
        s += v[i];
    }
    sh[threadIdx.x] = s; __syncthreads();
    for (int o = 1; o < SCAN_BLK; o <<= 1) {
        int t = (threadIdx.x >= o) ? sh[threadIdx.x - o] : 0;
        __syncthreads();
        sh[threadIdx.x] += t;
        __syncthreads();
    }
    int off = bsum[blockIdx.x] + sh[threadIdx.x] - s;
    #pragma unroll
    for (int i = 0; i < SCAN_ITEMS; ++i) {
        int idx = base + i;
        if (idx < n) {
            offs[idx] = off;
            cursor[idx] = off;
            off += v[i];
            if (idx == n - 1) offs[n] = off;
        }
    }
}

__global__ __launch_bounds__(256) void scatter_all_kernel(
    EdgeArgs a, int* __restrict__ cursor, int* __restrict__ csr_src)
{
    int gid = blockIdx.x * 256 + threadIdx.x;
    int E = a.E;
    if (gid >= 3 * E) return;
    int t = (gid < E) ? 0 : ((gid < 2 * E) ? 1 : 2);
    int e = gid - t * E;
    int p = atomicAdd(&cursor[a.base[t] + a.dst[t][e]], 1);
    csr_src[p] = a.src[t][e];
}

// ---------- fused per-dst softmax + aggregate over CSR segments, all etypes ----------
struct AggArgs {
    const unsigned short* K[3];
    const unsigned short* Q[3];
    const unsigned short* V[3];
    const float* pri[3];
    unsigned short* T[3];
};

__global__ __launch_bounds__(256) void csr_agg_all_kernel(
    const int* __restrict__ offs, const int* __restrict__ csr_src,
    AggArgs a, int n_b, int n_a)
{
    int gid = blockIdx.x * 256 + threadIdx.x;
    int s = gid >> 3, h = gid & 7;
    int S = 2 * n_b + n_a;
    if (s >= S) return;
    int t = (s < n_b) ? 0 : ((s < 2 * n_b) ? 1 : 2);
    int n = s - ((t == 2) ? 2 * n_b : t * n_b);

    const unsigned short *Kp, *Qp, *Vp; const float* prip; unsigned short* Tp;
    if (t == 0)      { Kp=a.K[0]; Qp=a.Q[0]; Vp=a.V[0]; prip=a.pri[0]; Tp=a.T[0]; }
    else if (t == 1) { Kp=a.K[1]; Qp=a.Q[1]; Vp=a.V[1]; prip=a.pri[1]; Tp=a.T[1]; }
    else             { Kp=a.K[2]; Qp=a.Q[2]; Vp=a.V[2]; prip=a.pri[2]; Tp=a.T[2]; }

    int e0 = offs[s], e1 = offs[s + 1];

    const uint4* qp = (const uint4*)(Qp + (size_t)n * D + h * DK);
    uint4 q0 = qp[0], q1 = qp[1];
    float qv[16];
    unpack8(q0, qv); unpack8(q1, qv + 8);
    float ps = prip[h] * 0.25f;

    float acc[16];
    #pragma unroll
    for (int i = 0; i < 16; ++i) acc[i] = 0.f;
    float den = 0.f;

    for (int e = e0; e < e1; ++e) {
        int sc = csr_src[e];
        const uint4* kp = (const uint4*)(Kp + (size_t)sc * D + h * DK);
        uint4 k0 = kp[0], k1 = kp[1];
        float kv[16];
        unpack8(k0, kv); unpack8(k1, kv + 8);
        float aa = 0.f;
        #pragma unroll
        for (int i = 0; i < 16; ++i) aa = fmaf(kv[i], qv[i], aa);
        float ea = __expf(aa * ps);
        den += ea;
        const uint4* vp = (const uint4*)(Vp + (size_t)sc * D + h * DK);
        uint4 v0 = vp[0], v1 = vp[1];
        float vv[16];
        unpack8(v0, vv); unpack8(v1, vv + 8);
        #pragma unroll
        for (int i = 0; i < 16; ++i) acc[i] = fmaf(ea, vv[i], acc[i]);
    }
    float inv = 1.f / fmaxf(den, 1e-9f);
    unsigned short ob[16];
    #pragma unroll
    for (int i = 0; i < 16; ++i) ob[i] = f2bf(acc[i] * inv);
    uint4 o0, o1;
    o0.x = pack2(ob[0], ob[1]);   o0.y = pack2(ob[2], ob[3]);
    o0.z = pack2(ob[4], ob[5]);   o0.w = pack2(ob[6], ob[7]);
    o1.x = pack2(ob[8], ob[9]);   o1.y = pack2(ob[10], ob[11]);
    o1.z = pack2(ob[12], ob[13]); o1.w = pack2(ob[14], ob[15]);
    unsigned short* tp = Tp + (size_t)n * D + h * DK;
    *(uint4*)tp = o0;
    *(uint4*)(tp + 8) = o1;
}

extern "C" void kernel_launch(void* const* d_in, const int* in_sizes, int n_in,
                              void* d_out, int out_size, void* d_ws, size_t ws_size,
                              hipStream_t stream) {
    const float* x_a = (const float*)d_in[0];
    const float* x_b = (const float*)d_in[1];
    const int* src_ab = (const int*)d_in[2];
    const int* dst_ab = (const int*)d_in[3];
    const int* src_ba = (const int*)d_in[4];
    const int* dst_ba = (const int*)d_in[5];
    const int* src_bb = (const int*)d_in[6];
    const int* dst_bb = (const int*)d_in[7];
    const float* Wk_a = (const float*)d_in[8];  const float* bk_a = (const float*)d_in[9];
    const float* Wq_a = (const float*)d_in[10]; const float* bq_a = (const float*)d_in[11];
    const float* Wv_a = (const float*)d_in[12]; const float* bv_a = (const float*)d_in[13];
    const float* Wa_a = (const float*)d_in[14]; const float* ba_a = (const float*)d_in[15];
    const float* skip_a = (const float*)d_in[16];
    const float* Wk_b = (const float*)d_in[17]; const float* bk_b = (const float*)d_in[18];
    const float* Wq_b = (const float*)d_in[19]; const float* bq_b = (const float*)d_in[20];
    const float* Wv_b = (const float*)d_in[21]; const float* bv_b = (const float*)d_in[22];
    const float* Wa_b = (const float*)d_in[23]; const float* ba_b = (const float*)d_in[24];
    const float* skip_b = (const float*)d_in[25];
    const float* pri_ab = (const float*)d_in[26];
    const float* att_ab = (const float*)d_in[27];
    const float* msg_ab = (const float*)d_in[28];
    const float* pri_ba = (const float*)d_in[29];
    const float* att_ba = (const float*)d_in[30];
    const float* msg_ba = (const float*)d_in[31];
    const float* pri_bb = (const float*)d_in[32];
    const float* att_bb = (const float*)d_in[33];
    const float* msg_bb = (const float*)d_in[34];

    const int n_a = in_sizes[0] / D;
    const int n_b = in_sizes[1] / D;
    const int E = in_sizes[2];
    const int S = 2 * n_b + n_a;

    size_t off = 0;
    char* base = (char*)d_ws;
    auto alloc = [&](size_t bytes) -> void* {
        void* r = base + off;
        off += (bytes + 255) & ~(size_t)255;
        return r;
    };
    unsigned short* k_a = (unsigned short*)alloc((size_t)n_a * D * 2);
    unsigned short* k_b = (unsigned short*)alloc((size_t)n_b * D * 2);
    unsigned short* qab = (unsigned short*)alloc((size_t)n_b * D * 2);
    unsigned short* qbb = (unsigned short*)alloc((size_t)n_b * D * 2);
    unsigned short* qba = (unsigned short*)alloc((size_t)n_a * D * 2);
    unsigned short* vab = (unsigned short*)alloc((size_t)n_a * D * 2);
    unsigned short* vbb = (unsigned short*)alloc((size_t)n_b * D * 2);
    unsigned short* vba = (unsigned short*)alloc((size_t)n_b * D * 2);
    unsigned short* t_a  = (unsigned short*)alloc((size_t)n_a * D * 2);
    unsigned short* t_b1 = (unsigned short*)alloc((size_t)n_b * D * 2);
    unsigned short* t_b2 = (unsigned short*)alloc((size_t)n_b * D * 2);
    int* cnt    = (int*)alloc((size_t)S * 4);
    int* offs   = (int*)alloc(((size_t)S + 1) * 4);
    int* cursor = (int*)alloc((size_t)S * 4);
    int* csr_src= (int*)alloc((size_t)3 * E * 4);
    int* bsum   = (int*)alloc(256 * 4);
    unsigned short* wt_plain[4];
    for (int i = 0; i < 4; ++i) wt_plain[i] = (unsigned short*)alloc((size_t)D * D * 2);
    unsigned short* wt_fold[6];
    float* bf_fold[6];
    for (int i = 0; i < 6; ++i) {
        wt_fold[i] = (unsigned short*)alloc((size_t)D * D * 2);
        bf_fold[i] = (float*)alloc((size_t)D * 4);
    }

    // plain transposes: Wk_a, Wk_b, Wa_a, Wa_b
    WTIn win; WTOut wout;
    const float* worig[4] = {Wk_a, Wk_b, Wa_a, Wa_b};
    for (int i = 0; i < 4; ++i) { win.w[i] = worig[i]; wout.wt[i] = wt_plain[i]; }
    wt_prep_kernel<<<64, 256, 0, stream>>>(win, wout);

    // folds: 0:qab(Wq_b,att_ab) 1:qbb(Wq_b,att_bb) 2:qba(Wq_a,att_ba)
    //        3:vab(Wv_a,msg_ab) 4:vbb(Wv_b,msg_bb) 5:vba(Wv_b,msg_ba)
    FoldArgs fa;
    const float* fW[6] = {Wq_b, Wq_b, Wq_a, Wv_a, Wv_b, Wv_b};
    const float* fR[6] = {att_ab, att_bb, att_ba, msg_ab, msg_bb, msg_ba};
    const float* fb[6] = {bq_b, bq_b, bq_a, bv_a, bv_b, bv_b};
    int fm[6] = {0, 0, 0, 1, 1, 1};
    for (int i = 0; i < 6; ++i) {
        fa.W[i] = fW[i]; fa.R[i] = fR[i]; fa.b[i] = fb[i];
        fa.WT[i] = wt_fold[i]; fa.bf[i] = bf_fold[i]; fa.mode[i] = fm[i];
    }
    fold_kernel<<<48, 256, 0, stream>>>(fa);

    // combined CSR build
    EdgeArgs ea;
    ea.src[0] = src_ab; ea.dst[0] = dst_ab;
    ea.src[1] = src_bb; ea.dst[1] = dst_bb;
    ea.src[2] = src_ba; ea.dst[2] = dst_ba;
    ea.base[0] = 0; ea.base[1] = n_b; ea.base[2] = 2 * n_b;
    ea.E = E;
    hipMemsetAsync(cnt, 0, (size_t)S * 4, stream);
    int ge3 = (3 * E + 255) / 256;
    hist_all_kernel<<<ge3, 256, 0, stream>>>(ea, cnt);
    int nb = (S + SCAN_TILE - 1) / SCAN_TILE;
    scan1_kernel<<<nb, SCAN_BLK, 0, stream>>>(cnt, bsum, S);
    scan2_kernel<<<1, 64, 0, stream>>>(bsum, nb);
    scan3_kernel<<<nb, SCAN_BLK, 0, stream>>>(cnt, bsum, offs, cursor, S);
    scatter_all_kernel<<<ge3, 256, 0, stream>>>(ea, cursor, csr_src);

    // projections with folded weights
    const int gb_a = (n_a + 63) / 64;
    const int gb_b = (n_b + 63) / 64;
    {
        ProjArgs<3> pa;
        pa.wt[0] = wt_plain[0]; pa.bias[0] = bk_a;       pa.out[0] = k_a;
        pa.wt[1] = wt_fold[2];  pa.bias[1] = bf_fold[2]; pa.out[1] = qba;
        pa.wt[2] = wt_fold[3];  pa.bias[2] = bf_fold[3]; pa.out[2] = vab;
        proj_all_kernel<3><<<gb_a, 256, 0, stream>>>(x_a, pa, n_a);
    }
    {
        ProjArgs<5> pb;
        pb.wt[0] = wt_plain[1]; pb.bias[0] = bk_b;       pb.out[0] = k_b;
        pb.wt[1] = wt_fold[0];  pb.bias[1] = bf_fold[0]; pb.out[1] = qab;
        pb.wt[2] = wt_fold[1];  pb.bias[2] = bf_fold[1]; pb.out[2] = qbb;
        pb.wt[3] = wt_fold[4];  pb.bias[3] = bf_fold[4]; pb.out[3] = vbb;
        pb.wt[4] = wt_fold[5];  pb.bias[4] = bf_fold[5]; pb.out[4] = vba;
        proj_all_kernel<5><<<gb_b, 256, 0, stream>>>(x_b, pb, n_b);
    }

    // fused aggregate (all etypes)
    AggArgs aa;
    aa.K[0] = k_a; aa.Q[0] = qab; aa.V[0] = vab; aa.pri[0] = pri_ab; aa.T[0] = t_b1;
    aa.K[1] = k_b; aa.Q[1] = qbb; aa.V[1] = vbb; aa.pri[1] = pri_bb; aa.T[1] = t_b2;
    aa.K[2] = k_b; aa.Q[2] = qba; aa.V[2] = vba; aa.pri[2] = pri_ba; aa.T[2] = t_a;
    int gs = (S * H + 255) / 256;
    csr_agg_all_kernel<<<gs, 256, 0, stream>>>(offs, csr_src, aa, n_b, n_a);

    // final skip-connection GEMMs (MFMA)
    float* out_a = (float*)d_out;
    float* out_b = (float*)d_out + (size_t)n_a * D;
    out_gemm_mfma_kernel<1><<<gb_a, 256, 0, stream>>>(t_a, nullptr, wt_plain[2], ba_a, skip_a, x_a, out_a, n_a);
    out_gemm_mfma_kernel<2><<<gb_b, 256, 0, stream>>>(t_b1, t_b2, wt_plain[3], ba_b, skip_b, x_b, out_b, n_b);
}